// Round 1
// baseline (617.790 us; speedup 1.0000x reference)
//
#include <hip/hip_runtime.h>

// Problem constants
#define BATCH 32
#define LP 1024
#define LQ 1024
#define LV 512
#define DIM 512

typedef __bf16 bf16x8 __attribute__((ext_vector_type(8)));
typedef float f32x4 __attribute__((ext_vector_type(4)));
typedef unsigned short ushort_t;

// fp32 -> bf16 round-to-nearest-even (raw bits)
__device__ __forceinline__ ushort_t f2bf(float f) {
  unsigned int u = __float_as_uint(f);
  unsigned int r = (u + 0x7FFFu + ((u >> 16) & 1u)) >> 16;
  return (ushort_t)r;
}

__device__ __forceinline__ void async16(const void* g, void* l) {
  __builtin_amdgcn_global_load_lds(
      (const __attribute__((address_space(1))) unsigned int*)g,
      (__attribute__((address_space(3))) unsigned int*)l, 16, 0, 0);
}

// -------- transpose + fp32->bf16 convert: in [B][R][C] f32 -> out [B][C][R] bf16
__global__ void transpose_cvt(const float* __restrict__ in, ushort_t* __restrict__ out,
                              int R, int C) {
  __shared__ ushort_t tile[32][33];
  int b = blockIdx.z;
  int c0 = blockIdx.x * 32, r0 = blockIdx.y * 32;
  const float* inb = in + (size_t)b * R * C;
  ushort_t* outb = out + (size_t)b * R * C;
  int x = threadIdx.x, y = threadIdx.y;
#pragma unroll
  for (int k = 0; k < 4; ++k) {
    int r = r0 + y + k * 8;
    tile[y + k * 8][x] = f2bf(inb[(size_t)r * C + c0 + x]);
  }
  __syncthreads();
#pragma unroll
  for (int k = 0; k < 4; ++k) {
    int c = c0 + y + k * 8;
    outb[(size_t)c * R + r0 + x] = tile[x][y + k * 8];
  }
}

// -------- score kernel: P = exp(scale * A·Bm^T) (bf16, unnormalized), lsum += row sums
// A: [B][M][DIM] f32, Bm: [B][N][DIM] f32, P: [B][M][N] bf16, lsum: [B][M] f32 (pre-zeroed)
// 128x128 tile, BK=32, 4 waves (each 64x64 = 4x4 MFMA 16x16x32 tiles)
__global__ __launch_bounds__(256)
void score_kernel(const float* __restrict__ A, const float* __restrict__ Bm,
                  ushort_t* __restrict__ P, float* __restrict__ lsum,
                  int M, int N) {
  __shared__ ushort_t sA[128 * 40];  // +8 pad: stride 80B kills 16-way b128 conflicts
  __shared__ ushort_t sB[128 * 40];
  int b = blockIdx.z;
  int m0 = blockIdx.x * 128, n0 = blockIdx.y * 128;
  const float* Ab = A + ((size_t)b * M + m0) * DIM;
  const float* Bb = Bm + ((size_t)b * N + n0) * DIM;
  int tid = threadIdx.x;
  int lane = tid & 63, w = tid >> 6;
  int wm = w >> 1, wn = w & 1;
  int quad = lane >> 4, low = lane & 15;

  f32x4 acc[4][4];
  f32x4 zero = {0.f, 0.f, 0.f, 0.f};
#pragma unroll
  for (int i = 0; i < 4; ++i)
#pragma unroll
    for (int j = 0; j < 4; ++j) acc[i][j] = zero;

  for (int kt = 0; kt < DIM; kt += 32) {
    // stage A-tile and B-tile (fp32 -> bf16) : 128 rows x 32 cols each
#pragma unroll
    for (int i = 0; i < 4; ++i) {
      int c = i * 256 + tid;          // float4-chunk id, 1024 total
      int r = c >> 3, c4 = c & 7;
      float4 f = *(const float4*)(Ab + (size_t)r * DIM + kt + c4 * 4);
      ushort4 h;
      h.x = f2bf(f.x); h.y = f2bf(f.y); h.z = f2bf(f.z); h.w = f2bf(f.w);
      *(ushort4*)&sA[r * 40 + c4 * 4] = h;
    }
#pragma unroll
    for (int i = 0; i < 4; ++i) {
      int c = i * 256 + tid;
      int r = c >> 3, c4 = c & 7;
      float4 f = *(const float4*)(Bb + (size_t)r * DIM + kt + c4 * 4);
      ushort4 h;
      h.x = f2bf(f.x); h.y = f2bf(f.y); h.z = f2bf(f.z); h.w = f2bf(f.w);
      *(ushort4*)&sB[r * 40 + c4 * 4] = h;
    }
    __syncthreads();
    bf16x8 af[4], bfr[4];
#pragma unroll
    for (int t = 0; t < 4; ++t) {
      af[t]  = *(const bf16x8*)&sA[(wm * 64 + t * 16 + low) * 40 + quad * 8];
      bfr[t] = *(const bf16x8*)&sB[(wn * 64 + t * 16 + low) * 40 + quad * 8];
    }
#pragma unroll
    for (int i = 0; i < 4; ++i)
#pragma unroll
      for (int j = 0; j < 4; ++j)
        acc[i][j] = __builtin_amdgcn_mfma_f32_16x16x32_bf16(af[i], bfr[j], acc[i][j], 0, 0, 0);
    __syncthreads();
  }

  // epilogue: exp (no max-subtraction needed: |scores| <= ~5.5), bf16 store, row-sum atomics
  const float sc = 0.04419417382415922f;  // 1/sqrt(512)
  size_t pb = (size_t)b * M * N;
#pragma unroll
  for (int i = 0; i < 4; ++i) {
    int gr0 = m0 + wm * 64 + i * 16 + quad * 4;
#pragma unroll
    for (int r = 0; r < 4; ++r) {
      int gr = gr0 + r;
      float rs = 0.f;
#pragma unroll
      for (int j = 0; j < 4; ++j) {
        float p = __expf(acc[i][j][r] * sc);
        rs += p;
        int gc = n0 + wn * 64 + j * 16 + low;
        P[pb + (size_t)gr * N + gc] = f2bf(p);
      }
      rs += __shfl_xor(rs, 1);
      rs += __shfl_xor(rs, 2);
      rs += __shfl_xor(rs, 4);
      rs += __shfl_xor(rs, 8);
      if (low == 0) atomicAdd(&lsum[(size_t)b * M + gr], rs);
    }
  }
}

// -------- gemm_bt: out[m][n] = (sum_k A[m][k]*BT[n][k]) * (DIV ? 1/l[m] : 1)
// A: [B][M][K] bf16, BT: [B][N][K] bf16, out: [B][M][N] f32, out2 optional bf16 copy
// m97 structure: global_load_lds width 16, 128x128 tile, BK=32
template <bool DIV, bool OUT2>
__global__ __launch_bounds__(256)
void gemm_bt_kernel(const ushort_t* __restrict__ A, const ushort_t* __restrict__ BT,
                    const float* __restrict__ lsum, float* __restrict__ out,
                    ushort_t* __restrict__ out2, int M, int N, int K) {
  __shared__ ushort_t sA[128 * 32];  // no padding: global_load_lds needs contiguous
  __shared__ ushort_t sB[128 * 32];
  int b = blockIdx.z;
  int m0 = blockIdx.x * 128, n0 = blockIdx.y * 128;
  const ushort_t* Ab = A + ((size_t)b * M + m0) * K;
  const ushort_t* Bb = BT + ((size_t)b * N + n0) * K;
  int tid = threadIdx.x;
  int lane = tid & 63, w = tid >> 6;
  int wm = w >> 1, wn = w & 1;
  int quad = lane >> 4, low = lane & 15;

  f32x4 acc[4][4];
  f32x4 zero = {0.f, 0.f, 0.f, 0.f};
#pragma unroll
  for (int i = 0; i < 4; ++i)
#pragma unroll
    for (int j = 0; j < 4; ++j) acc[i][j] = zero;

  for (int kt = 0; kt < K; kt += 32) {
    // stage: each wave issues 2 A-chunks + 2 B-chunks of 64 lanes x 16B
#pragma unroll
    for (int j = 0; j < 2; ++j) {
      int cb = w * 128 + j * 64;      // wave-uniform chunk base
      int c = cb + lane;              // 16B-chunk id in tile (4 chunks per 32-elem row)
      int r = c >> 2, kc = c & 3;
      async16(Ab + (size_t)r * K + kt + kc * 8, &sA[cb * 8]);
      async16(Bb + (size_t)r * K + kt + kc * 8, &sB[cb * 8]);
    }
    __syncthreads();  // drains vmcnt before barrier
    bf16x8 af[4], bfr[4];
#pragma unroll
    for (int t = 0; t < 4; ++t) {
      af[t]  = *(const bf16x8*)&sA[(wm * 64 + t * 16 + low) * 32 + quad * 8];
      bfr[t] = *(const bf16x8*)&sB[(wn * 64 + t * 16 + low) * 32 + quad * 8];
    }
#pragma unroll
    for (int i = 0; i < 4; ++i)
#pragma unroll
      for (int j = 0; j < 4; ++j)
        acc[i][j] = __builtin_amdgcn_mfma_f32_16x16x32_bf16(af[i], bfr[j], acc[i][j], 0, 0, 0);
    __syncthreads();
  }

  size_t ob = (size_t)b * M * N;
#pragma unroll
  for (int i = 0; i < 4; ++i) {
    int gr0 = m0 + wm * 64 + i * 16 + quad * 4;
#pragma unroll
    for (int r = 0; r < 4; ++r) {
      int gr = gr0 + r;
      float inv = 1.f;
      if (DIV) inv = 1.f / lsum[(size_t)b * M + gr];
#pragma unroll
      for (int j = 0; j < 4; ++j) {
        int gc = n0 + wn * 64 + j * 16 + low;
        float o = acc[i][j][r] * inv;
        out[ob + (size_t)gr * N + gc] = o;
        if (OUT2) out2[ob + (size_t)gr * N + gc] = f2bf(o);
      }
    }
  }
}

extern "C" void kernel_launch(void* const* d_in, const int* in_sizes, int n_in,
                              void* d_out, int out_size, void* d_ws, size_t ws_size,
                              hipStream_t stream) {
  (void)in_sizes; (void)n_in; (void)out_size; (void)ws_size;
  const float* pre = (const float*)d_in[0];
  const float* q   = (const float*)d_in[1];
  const float* v   = (const float*)d_in[2];

  float* out      = (float*)d_out;
  float* wc       = out;                                   // weightedContext [B][LQ][DIM]
  float* energy   = out + (size_t)BATCH * LQ * DIM;        // energy          [B][LQ][DIM]
  float* precomp  = out + 2 * (size_t)BATCH * LQ * DIM;    // precompute      [B][LP][DIM]

  // workspace layout (all 256B aligned)
  char* ws = (char*)d_ws;
  size_t off = 0;
  auto alloc = [&](size_t bytes) {
    void* p = ws + off;
    off += (bytes + 255) & ~(size_t)255;
    return p;
  };
  ushort_t* qT  = (ushort_t*)alloc((size_t)BATCH * DIM * LQ * 2);  // q^T  bf16 [B][DIM][LQ]
  ushort_t* vT  = (ushort_t*)alloc((size_t)BATCH * DIM * LV * 2);  // v^T  bf16 [B][DIM][LV]
  ushort_t* Pp  = (ushort_t*)alloc((size_t)BATCH * LP * LQ * 2);   // exp scores stream1
  ushort_t* Pe  = (ushort_t*)alloc((size_t)BATCH * LQ * LV * 2);   // exp scores stream2
  ushort_t* Ebf = (ushort_t*)alloc((size_t)BATCH * LQ * DIM * 2);  // energy bf16 copy
  float* lp = (float*)alloc((size_t)BATCH * LP * 4);               // row sums stream1
  float* le = (float*)alloc((size_t)BATCH * LQ * 4);               // row sums stream2 (contiguous after lp)

  hipMemsetAsync(lp, 0, (size_t)BATCH * (LP + LQ) * 4, stream);

  transpose_cvt<<<dim3(DIM / 32, LQ / 32, BATCH), dim3(32, 8), 0, stream>>>(q, qT, LQ, DIM);
  transpose_cvt<<<dim3(DIM / 32, LV / 32, BATCH), dim3(32, 8), 0, stream>>>(v, vT, LV, DIM);

  // stream1 scores: Sp = pre . q^T  -> Pp [B][LP][LQ], lp
  score_kernel<<<dim3(LP / 128, LQ / 128, BATCH), 256, 0, stream>>>(pre, q, Pp, lp, LP, LQ);
  // stream2 scores: Se = q . v^T    -> Pe [B][LQ][LV], le
  score_kernel<<<dim3(LQ / 128, LV / 128, BATCH), 256, 0, stream>>>(q, v, Pe, le, LQ, LV);

  // precompute = (Pp . q) / lp      : A=Pp [LP][LQ], BT=qT [DIM][LQ]
  gemm_bt_kernel<true, false><<<dim3(LP / 128, DIM / 128, BATCH), 256, 0, stream>>>(
      Pp, qT, lp, precomp, nullptr, LP, DIM, LQ);
  // energy = (Pe . v) / le          : A=Pe [LQ][LV], BT=vT [DIM][LV]; also bf16 copy
  gemm_bt_kernel<true, true><<<dim3(LQ / 128, DIM / 128, BATCH), 256, 0, stream>>>(
      Pe, vT, le, energy, Ebf, LQ, DIM, LV);
  // weightedContext = Ebf . v       : A=Ebf [LQ][DIM], BT=vT [DIM][LV]
  gemm_bt_kernel<false, false><<<dim3(LQ / 128, DIM / 128, BATCH), 256, 0, stream>>>(
      Ebf, vT, nullptr, wc, nullptr, LQ, DIM, LV);
}

// Round 2
// 598.189 us; speedup vs baseline: 1.0328x; 1.0328x over previous
//
#include <hip/hip_runtime.h>

// Problem constants
#define BATCH 32
#define LP 1024
#define LQ 1024
#define LV 512
#define DIM 512

typedef __bf16 bf16x8 __attribute__((ext_vector_type(8)));
typedef float f32x4 __attribute__((ext_vector_type(4)));
typedef unsigned short ushort_t;
typedef unsigned short us8 __attribute__((ext_vector_type(8)));

// fp32 -> bf16 round-to-nearest-even (raw bits)
__device__ __forceinline__ ushort_t f2bf(float f) {
  unsigned int u = __float_as_uint(f);
  unsigned int r = (u + 0x7FFFu + ((u >> 16) & 1u)) >> 16;
  return (ushort_t)r;
}

__device__ __forceinline__ void async16(const void* g, void* l) {
  __builtin_amdgcn_global_load_lds(
      (const __attribute__((address_space(1))) unsigned int*)g,
      (__attribute__((address_space(3))) unsigned int*)l, 16, 0, 0);
}

// -------- plain fp32 -> bf16 convert (row-major copy), 8 elems/thread
__global__ __launch_bounds__(256)
void cvt_kernel(const float* __restrict__ in, ushort_t* __restrict__ out) {
  int i = blockIdx.x * blockDim.x + threadIdx.x;
  const float4* p = (const float4*)in;
  float4 a = p[i * 2], b = p[i * 2 + 1];
  us8 h;
  h[0] = f2bf(a.x); h[1] = f2bf(a.y); h[2] = f2bf(a.z); h[3] = f2bf(a.w);
  h[4] = f2bf(b.x); h[5] = f2bf(b.y); h[6] = f2bf(b.z); h[7] = f2bf(b.w);
  *(us8*)&out[(size_t)i * 8] = h;
}

// -------- transpose + convert: in [B][R][C] f32 -> outT [B][C][R] bf16, outR [B][R][C] bf16
__global__ void transpose_cvt(const float* __restrict__ in, ushort_t* __restrict__ outT,
                              ushort_t* __restrict__ outR, int R, int C) {
  __shared__ ushort_t tile[32][33];
  int b = blockIdx.z;
  int c0 = blockIdx.x * 32, r0 = blockIdx.y * 32;
  const float* inb = in + (size_t)b * R * C;
  ushort_t* outTb = outT + (size_t)b * R * C;
  ushort_t* outRb = outR + (size_t)b * R * C;
  int x = threadIdx.x, y = threadIdx.y;
#pragma unroll
  for (int k = 0; k < 4; ++k) {
    int r = r0 + y + k * 8;
    ushort_t h = f2bf(inb[(size_t)r * C + c0 + x]);
    tile[y + k * 8][x] = h;
    outRb[(size_t)r * C + c0 + x] = h;   // row-major bf16 copy (coalesced 64B/row-seg)
  }
  __syncthreads();
#pragma unroll
  for (int k = 0; k < 4; ++k) {
    int c = c0 + y + k * 8;
    outTb[(size_t)c * R + r0 + x] = tile[x][y + k * 8];
  }
}

// -------- score kernel (bf16 inputs, m97 structure): P = exp(scale*A·BT^T) + row sums
// A: [B][M][K] bf16, BT: [B][N][K] bf16 (k-contiguous), P: [B][M][N] bf16,
// lsum: [B][M] f32 (pre-zeroed). 128x128 tile, BK=32, 4 waves.
__global__ __launch_bounds__(256)
void score_bf16_kernel(const ushort_t* __restrict__ A, const ushort_t* __restrict__ BT,
                       ushort_t* __restrict__ P, float* __restrict__ lsum,
                       int M, int N, int K) {
  __shared__ ushort_t sA[128 * 32];  // contiguous: global_load_lds layout
  __shared__ ushort_t sB[128 * 32];
  int b = blockIdx.z;
  int m0 = blockIdx.x * 128, n0 = blockIdx.y * 128;
  const ushort_t* Ab = A + ((size_t)b * M + m0) * K;
  const ushort_t* Bb = BT + ((size_t)b * N + n0) * K;
  int tid = threadIdx.x;
  int lane = tid & 63, w = tid >> 6;
  int wm = w >> 1, wn = w & 1;
  int quad = lane >> 4, low = lane & 15;

  f32x4 acc[4][4];
  f32x4 zero = {0.f, 0.f, 0.f, 0.f};
#pragma unroll
  for (int i = 0; i < 4; ++i)
#pragma unroll
    for (int j = 0; j < 4; ++j) acc[i][j] = zero;

  for (int kt = 0; kt < K; kt += 32) {
#pragma unroll
    for (int j = 0; j < 2; ++j) {
      int cb = w * 128 + j * 64;   // wave-uniform chunk base
      int c = cb + lane;           // 16B-chunk id (4 per 32-elem row)
      int r = c >> 2, kc = c & 3;
      async16(Ab + (size_t)r * K + kt + kc * 8, &sA[cb * 8]);
      async16(Bb + (size_t)r * K + kt + kc * 8, &sB[cb * 8]);
    }
    __syncthreads();
    bf16x8 af[4], bfr[4];
#pragma unroll
    for (int t = 0; t < 4; ++t) {
      af[t]  = *(const bf16x8*)&sA[(wm * 64 + t * 16 + low) * 32 + quad * 8];
      bfr[t] = *(const bf16x8*)&sB[(wn * 64 + t * 16 + low) * 32 + quad * 8];
    }
#pragma unroll
    for (int i = 0; i < 4; ++i)
#pragma unroll
      for (int j = 0; j < 4; ++j)
        acc[i][j] = __builtin_amdgcn_mfma_f32_16x16x32_bf16(af[i], bfr[j], acc[i][j], 0, 0, 0);
    __syncthreads();
  }

  const float sc = 0.04419417382415922f;  // 1/sqrt(512)
  size_t pb = (size_t)b * M * N;
#pragma unroll
  for (int i = 0; i < 4; ++i) {
    int gr0 = m0 + wm * 64 + i * 16 + quad * 4;
#pragma unroll
    for (int r = 0; r < 4; ++r) {
      int gr = gr0 + r;
      float rs = 0.f;
#pragma unroll
      for (int j = 0; j < 4; ++j) {
        float p = __expf(acc[i][j][r] * sc);  // |scores| <= ~5.5: no max-sub needed
        rs += p;
        int gc = n0 + wn * 64 + j * 16 + low;
        P[pb + (size_t)gr * N + gc] = f2bf(p);
      }
      rs += __shfl_xor(rs, 1);
      rs += __shfl_xor(rs, 2);
      rs += __shfl_xor(rs, 4);
      rs += __shfl_xor(rs, 8);
      if (low == 0) atomicAdd(&lsum[(size_t)b * M + gr], rs);
    }
  }
}

// -------- gemm_bt: out[m][n] = (sum_k A[m][k]*BT[n][k]) * (DIV ? 1/l[m] : 1)
template <bool DIV, bool OUT2>
__global__ __launch_bounds__(256)
void gemm_bt_kernel(const ushort_t* __restrict__ A, const ushort_t* __restrict__ BT,
                    const float* __restrict__ lsum, float* __restrict__ out,
                    ushort_t* __restrict__ out2, int M, int N, int K) {
  __shared__ ushort_t sA[128 * 32];
  __shared__ ushort_t sB[128 * 32];
  int b = blockIdx.z;
  int m0 = blockIdx.x * 128, n0 = blockIdx.y * 128;
  const ushort_t* Ab = A + ((size_t)b * M + m0) * K;
  const ushort_t* Bb = BT + ((size_t)b * N + n0) * K;
  int tid = threadIdx.x;
  int lane = tid & 63, w = tid >> 6;
  int wm = w >> 1, wn = w & 1;
  int quad = lane >> 4, low = lane & 15;

  f32x4 acc[4][4];
  f32x4 zero = {0.f, 0.f, 0.f, 0.f};
#pragma unroll
  for (int i = 0; i < 4; ++i)
#pragma unroll
    for (int j = 0; j < 4; ++j) acc[i][j] = zero;

  for (int kt = 0; kt < K; kt += 32) {
#pragma unroll
    for (int j = 0; j < 2; ++j) {
      int cb = w * 128 + j * 64;
      int c = cb + lane;
      int r = c >> 2, kc = c & 3;
      async16(Ab + (size_t)r * K + kt + kc * 8, &sA[cb * 8]);
      async16(Bb + (size_t)r * K + kt + kc * 8, &sB[cb * 8]);
    }
    __syncthreads();
    bf16x8 af[4], bfr[4];
#pragma unroll
    for (int t = 0; t < 4; ++t) {
      af[t]  = *(const bf16x8*)&sA[(wm * 64 + t * 16 + low) * 32 + quad * 8];
      bfr[t] = *(const bf16x8*)&sB[(wn * 64 + t * 16 + low) * 32 + quad * 8];
    }
#pragma unroll
    for (int i = 0; i < 4; ++i)
#pragma unroll
      for (int j = 0; j < 4; ++j)
        acc[i][j] = __builtin_amdgcn_mfma_f32_16x16x32_bf16(af[i], bfr[j], acc[i][j], 0, 0, 0);
    __syncthreads();
  }

  size_t ob = (size_t)b * M * N;
#pragma unroll
  for (int i = 0; i < 4; ++i) {
    int gr0 = m0 + wm * 64 + i * 16 + quad * 4;
#pragma unroll
    for (int r = 0; r < 4; ++r) {
      int gr = gr0 + r;
      float inv = 1.f;
      if (DIV) inv = 1.f / lsum[(size_t)b * M + gr];
#pragma unroll
      for (int j = 0; j < 4; ++j) {
        int gc = n0 + wn * 64 + j * 16 + low;
        float o = acc[i][j][r] * inv;
        out[ob + (size_t)gr * N + gc] = o;
        if (OUT2) out2[ob + (size_t)gr * N + gc] = f2bf(o);
      }
    }
  }
}

extern "C" void kernel_launch(void* const* d_in, const int* in_sizes, int n_in,
                              void* d_out, int out_size, void* d_ws, size_t ws_size,
                              hipStream_t stream) {
  (void)in_sizes; (void)n_in; (void)out_size; (void)ws_size;
  const float* pre = (const float*)d_in[0];
  const float* q   = (const float*)d_in[1];
  const float* v   = (const float*)d_in[2];

  float* out      = (float*)d_out;
  float* wc       = out;                                   // weightedContext [B][LQ][DIM]
  float* energy   = out + (size_t)BATCH * LQ * DIM;        // energy          [B][LQ][DIM]
  float* precomp  = out + 2 * (size_t)BATCH * LQ * DIM;    // precompute      [B][LP][DIM]

  char* ws = (char*)d_ws;
  size_t off = 0;
  auto alloc = [&](size_t bytes) {
    void* p = ws + off;
    off += (bytes + 255) & ~(size_t)255;
    return p;
  };
  ushort_t* preB = (ushort_t*)alloc((size_t)BATCH * LP * DIM * 2);  // pre bf16 row-major
  ushort_t* qB   = (ushort_t*)alloc((size_t)BATCH * LQ * DIM * 2);  // q   bf16 row-major
  ushort_t* vB   = (ushort_t*)alloc((size_t)BATCH * LV * DIM * 2);  // v   bf16 row-major
  ushort_t* qT   = (ushort_t*)alloc((size_t)BATCH * DIM * LQ * 2);  // q^T bf16 [B][DIM][LQ]
  ushort_t* vT   = (ushort_t*)alloc((size_t)BATCH * DIM * LV * 2);  // v^T bf16 [B][DIM][LV]
  ushort_t* Pp   = (ushort_t*)alloc((size_t)BATCH * LP * LQ * 2);   // exp scores stream1
  ushort_t* Pe   = (ushort_t*)alloc((size_t)BATCH * LQ * LV * 2);   // exp scores stream2
  ushort_t* Ebf  = (ushort_t*)alloc((size_t)BATCH * LQ * DIM * 2);  // energy bf16 copy
  float* lp = (float*)alloc((size_t)BATCH * LP * 4);                // row sums stream1
  float* le = (float*)alloc((size_t)BATCH * LQ * 4);                // row sums stream2

  hipMemsetAsync(lp, 0, (size_t)BATCH * (LP + LQ) * 4, stream);

  // prep: bf16 copies (+transposes for the PV gemms)
  cvt_kernel<<<(size_t)BATCH * LP * DIM / 8 / 256, 256, 0, stream>>>(pre, preB);
  transpose_cvt<<<dim3(DIM / 32, LQ / 32, BATCH), dim3(32, 8), 0, stream>>>(q, qT, qB, LQ, DIM);
  transpose_cvt<<<dim3(DIM / 32, LV / 32, BATCH), dim3(32, 8), 0, stream>>>(v, vT, vB, LV, DIM);

  // stream1 scores: Pp = exp(sc * pre.q^T)  [B][LP][LQ]
  score_bf16_kernel<<<dim3(LP / 128, LQ / 128, BATCH), 256, 0, stream>>>(
      preB, qB, Pp, lp, LP, LQ, DIM);
  // stream2 scores: Pe = exp(sc * q.v^T)    [B][LQ][LV]
  score_bf16_kernel<<<dim3(LQ / 128, LV / 128, BATCH), 256, 0, stream>>>(
      qB, vB, Pe, le, LQ, LV, DIM);

  // precompute = (Pp . q) / lp   : A=Pp [LP][LQ], BT=qT [DIM][LQ]
  gemm_bt_kernel<true, false><<<dim3(LP / 128, DIM / 128, BATCH), 256, 0, stream>>>(
      Pp, qT, lp, precomp, nullptr, LP, DIM, LQ);
  // energy = (Pe . v) / le       : A=Pe [LQ][LV], BT=vT [DIM][LV]; also bf16 copy
  gemm_bt_kernel<true, true><<<dim3(LQ / 128, DIM / 128, BATCH), 256, 0, stream>>>(
      Pe, vT, le, energy, Ebf, LQ, DIM, LV);
  // weightedContext = Ebf . v    : A=Ebf [LQ][DIM], BT=vT [DIM][LV]
  gemm_bt_kernel<false, false><<<dim3(LQ / 128, DIM / 128, BATCH), 256, 0, stream>>>(
      Ebf, vT, nullptr, wc, nullptr, LQ, DIM, LV);
}